// Round 11
// baseline (67.211 us; speedup 1.0000x reference)
//
#include <hip/hip_runtime.h>
#include <hip/hip_bf16.h>

#define B_SZ  128
#define CH    64
#define T_LEN 4096
#define HID   32
#define INS   3

typedef __attribute__((ext_vector_type(8))) short short8;   // 8 bf16 (4 VGPRs)
typedef __attribute__((ext_vector_type(4))) float f32x4;
typedef __attribute__((address_space(1))) const float gfloat1;
typedef __attribute__((address_space(3))) float sfloat3;

__device__ inline unsigned short f2bf_bits(float f) {
  __hip_bfloat16 h = __float2bfloat16(f);
  union { __hip_bfloat16 h; unsigned short u; } cv;
  cv.h = h;
  return cv.u;
}

// ---------------------------------------------------------------------------
// Kernel 1: hypernetwork MLPs. One block per batch sample.
// Emits weight as bf16 in natural [b][o][i] order + fp32 bias.
// ---------------------------------------------------------------------------
__global__ __launch_bounds__(256) void hyper_mlp_kernel(
    const float* __restrict__ z,
    const float* __restrict__ w_w1, const float* __restrict__ w_b1,
    const float* __restrict__ w_g,  const float* __restrict__ w_beta,
    const float* __restrict__ w_w2, const float* __restrict__ w_b2,
    const float* __restrict__ b_w1, const float* __restrict__ b_b1,
    const float* __restrict__ b_g,  const float* __restrict__ b_beta,
    const float* __restrict__ b_w2, const float* __restrict__ b_b2,
    unsigned short* __restrict__ wbf,  // [B][CH_out][CH_in] bf16 bits
    float* __restrict__ bias)          // [B][CH]
{
  const int b   = blockIdx.x;
  const int tid = threadIdx.x;

  __shared__ float zs[INS];
  __shared__ float hraw[2][HID];
  __shared__ float hn[2][HID];

  if (tid < INS) zs[tid] = z[b * INS + tid];
  __syncthreads();

  if (tid < 2 * HID) {
    const int grp = tid >> 5;          // 0 = weight-MLP, 1 = bias-MLP
    const int j   = tid & 31;
    const float* w1 = grp ? b_w1 : w_w1;
    const float* b1 = grp ? b_b1 : w_b1;
    hraw[grp][j] = w1[j*3+0]*zs[0] + w1[j*3+1]*zs[1] + w1[j*3+2]*zs[2] + b1[j];
  }
  __syncthreads();

  if (tid < 2 * HID) {
    const int grp = tid >> 5;
    const int j   = tid & 31;
    float mu = 0.f;
    #pragma unroll
    for (int k = 0; k < HID; ++k) mu += hraw[grp][k];
    mu *= (1.0f / HID);
    float var = 0.f;
    #pragma unroll
    for (int k = 0; k < HID; ++k) { float d = hraw[grp][k] - mu; var += d * d; }
    var *= (1.0f / HID);
    const float r  = rsqrtf(var + 1e-5f);
    const float* g  = grp ? b_g    : w_g;
    const float* be = grp ? b_beta : w_beta;
    const float v = (hraw[grp][j] - mu) * r * g[j] + be[j];
    hn[grp][j] = fmaxf(v, 0.f);
  }
  __syncthreads();

  for (int m = tid; m < CH * CH; m += 256) {
    const float* row = w_w2 + m * HID;
    float acc = w_b2[m];
    #pragma unroll
    for (int i = 0; i < HID; ++i) acc += hn[0][i] * row[i];
    wbf[(size_t)b * CH * CH + m] = f2bf_bits(acc);
  }

  if (tid < CH) {
    const float* row = b_w2 + tid * HID;
    float acc = b_b2[tid];
    #pragma unroll
    for (int i = 0; i < HID; ++i) acc += hn[1][i] * row[i];
    bias[b * CH + tid] = acc;
  }
}

// ---------------------------------------------------------------------------
// Kernel 2: out[b] = W[b] (64x64) @ x[b] (64x4096) + bias via bf16 MFMA,
// x staged through LDS with global_load_lds (in-flight bytes live in the
// vmcnt queue, not VGPRs). Round-11 change vs round 10: pipeline depth 4->2
// chunks, LDS 66.5->32.5 KB -> 4 blocks/CU (16 waves/CU) so block-start
// prologues overlap other blocks' compute and the HBM queue stays fed by
// ~2x more concurrent streams.
// Per-wave vmcnt ledger (in-order): afrag(8)+bias(4), L0(4), L1(4).
//   WAITB(4): prologue+L0 retired, L1 still in flight. COMP0 (16 stores).
//   WAITB(16): retires exactly L1; S0 stays in flight. COMP1.
// Chunk LDS rows padded to 260 floats -> ds_read 2-way bank aliasing (free).
// ---------------------------------------------------------------------------
#define STAGE(C)                                                              \
  {                                                                           \
    _Pragma("unroll")                                                         \
    for (int q = 0; q < 4; ++q) {                                             \
      const int m = wid * 4 + q;                                              \
      const float* ga = xb + (size_t)(4 * m + rowin) * T_LEN + (C) * 64 + col4; \
      __builtin_amdgcn_global_load_lds((gfloat1*)ga,                          \
          (sfloat3*)(lds + (C) * 4160 + m * 260), 16, 0, 0);                  \
    }                                                                         \
  }

#define COMPUTE(C)                                                            \
  {                                                                           \
    f32x4 a0 = {bv[0][0], bv[0][1], bv[0][2], bv[0][3]};                      \
    f32x4 a1 = {bv[1][0], bv[1][1], bv[1][2], bv[1][3]};                      \
    f32x4 a2 = {bv[2][0], bv[2][1], bv[2][2], bv[2][3]};                      \
    f32x4 a3 = {bv[3][0], bv[3][1], bv[3][2], bv[3][3]};                      \
    _Pragma("unroll")                                                         \
    for (int ks = 0; ks < 2; ++ks) {                                          \
      union { short8 s; unsigned short u[8]; } bfv;                           \
      _Pragma("unroll")                                                       \
      for (int j = 0; j < 8; ++j) {                                           \
        const float f = lds[(C) * 4160 + (ks * 8 + g * 2 + (j >> 2)) * 260    \
                            + (j & 3) * 64 + tloc];                           \
        bfv.u[j] = f2bf_bits(f);                                              \
      }                                                                       \
      a0 = __builtin_amdgcn_mfma_f32_16x16x32_bf16(afrag[0][ks], bfv.s, a0, 0, 0, 0); \
      a1 = __builtin_amdgcn_mfma_f32_16x16x32_bf16(afrag[1][ks], bfv.s, a1, 0, 0, 0); \
      a2 = __builtin_amdgcn_mfma_f32_16x16x32_bf16(afrag[2][ks], bfv.s, a2, 0, 0, 0); \
      a3 = __builtin_amdgcn_mfma_f32_16x16x32_bf16(afrag[3][ks], bfv.s, a3, 0, 0, 0); \
    }                                                                         \
    float* os = op + (C) * 64;                                                \
    _Pragma("unroll")                                                         \
    for (int q = 0; q < 4; ++q) {                                             \
      os[(size_t)(0 * 16 + g * 4 + q) * T_LEN] = a0[q];                       \
      os[(size_t)(1 * 16 + g * 4 + q) * T_LEN] = a1[q];                       \
      os[(size_t)(2 * 16 + g * 4 + q) * T_LEN] = a2[q];                       \
      os[(size_t)(3 * 16 + g * 4 + q) * T_LEN] = a3[q];                       \
    }                                                                         \
  }

#define WAITB(N)                                                              \
  {                                                                           \
    asm volatile("s_waitcnt vmcnt(" #N ")" ::: "memory");                     \
    __builtin_amdgcn_s_barrier();                                             \
    asm volatile("" ::: "memory");                                            \
  }

__global__ __launch_bounds__(256, 4) void conv1x1_mfma(
    const float* __restrict__ x,
    const unsigned short* __restrict__ wbf,
    const float* __restrict__ bias,
    float* __restrict__ out)
{
  __shared__ __align__(16) float lds[2 * 4160];   // 33280 B -> 4 blocks/CU

  const int b     = blockIdx.y;
  const int tbi   = blockIdx.x;
  const int tid   = threadIdx.x;
  const int lane  = tid & 63;
  const int wid   = tid >> 6;       // 0..3 (uniform per wave)
  const int g     = lane >> 4;      // 16-lane group
  const int r     = lane & 15;
  const int rowin = lane >> 4;      // staging row-in-group
  const int col4  = (lane & 15) * 4;
  const int tloc  = wid * 16 + r;   // t within chunk

  // A-frags: wbf[b][ot*16 + r][ks*32 + g*8 + 0..7]  (8 x 16B loads)
  const unsigned short* wb = wbf + (size_t)b * CH * CH;
  short8 afrag[4][2];
  #pragma unroll
  for (int ot = 0; ot < 4; ++ot)
    #pragma unroll
    for (int ks = 0; ks < 2; ++ks)
      afrag[ot][ks] = *(const short8*)(wb + (ot * 16 + r) * CH + ks * 32 + g * 8);

  // bias for lane's output rows o = ot*16 + g*4 + q  (4 x 16B loads)
  float bv[4][4];
  #pragma unroll
  for (int ot = 0; ot < 4; ++ot) {
    const float4 t = *(const float4*)(bias + b * CH + ot * 16 + g * 4);
    bv[ot][0] = t.x; bv[ot][1] = t.y; bv[ot][2] = t.z; bv[ot][3] = t.w;
  }

  const float* xb = x   + (size_t)b * CH * T_LEN + tbi * 128;
  float*       op = out + (size_t)b * CH * T_LEN + tbi * 128 + tloc;

  STAGE(0)
  STAGE(1)

  WAITB(4)           // afrag+bias+L0 retired; L1 (4) still in flight
  COMPUTE(0)

  WAITB(16)          // L1 retired; S0 (16) stays in flight
  COMPUTE(1)
}

extern "C" void kernel_launch(void* const* d_in, const int* in_sizes, int n_in,
                              void* d_out, int out_size, void* d_ws, size_t ws_size,
                              hipStream_t stream) {
  const float* x      = (const float*)d_in[0];
  const float* z      = (const float*)d_in[1];
  const float* w_w1   = (const float*)d_in[2];
  const float* w_b1   = (const float*)d_in[3];
  const float* w_g    = (const float*)d_in[4];
  const float* w_beta = (const float*)d_in[5];
  const float* w_w2   = (const float*)d_in[6];
  const float* w_b2   = (const float*)d_in[7];
  const float* b_w1   = (const float*)d_in[8];
  const float* b_b1   = (const float*)d_in[9];
  const float* b_g    = (const float*)d_in[10];
  const float* b_beta = (const float*)d_in[11];
  const float* b_w2   = (const float*)d_in[12];
  const float* b_b2   = (const float*)d_in[13];

  float* out = (float*)d_out;
  unsigned short* wbf = (unsigned short*)d_ws;                 // 128*4096 bf16 = 1 MB
  float* bias = (float*)((char*)d_ws + (size_t)B_SZ * CH * CH * sizeof(unsigned short));

  hyper_mlp_kernel<<<B_SZ, 256, 0, stream>>>(
      z, w_w1, w_b1, w_g, w_beta, w_w2, w_b2,
      b_w1, b_b1, b_g, b_beta, b_w2, b_b2, wbf, bias);

  dim3 grid(T_LEN / 128, B_SZ);
  conv1x1_mfma<<<grid, 256, 0, stream>>>(x, wbf, bias, out);
}